// Round 7
// baseline (1757.618 us; speedup 1.0000x reference)
//
#include <hip/hip_runtime.h>
#include <stdint.h>

// VQ: B=131072 rows, K=4096 codes, D=64, fp32 in/out.
// out = [B*D floats quantized_st][1 float loss]
//
// bf16 split-precision MFMA distance search (3-product exact-split, score
// error <~1e-3), per-row top-2 tracking, fp64 full rescan of near-tie rows.
// K-loop: B fragments loaded directly from L2-resident stage image into VGPRs,
// 4-deep register pipeline, no barriers in the loop. K-SPLIT: each wave scans
// half the codebook for 64 rows (waves 2w,2w+1 share rows, disjoint K halves),
// merged via LDS afterward -> 1024 blocks, 4 waves/SIMD occupancy.
constexpr int Bn = 131072, Kn = 4096, Dn = 64;
constexpr int NCHUNK = 256;          // K / 16 codes per chunk
constexpr int HCHUNK = 128;          // chunks per K-half
constexpr float TAU_S = 0.008f;      // score-gap flag threshold (~8x error bound)

typedef short bf16x8 __attribute__((ext_vector_type(8)));
typedef float f32x4  __attribute__((ext_vector_type(4)));

__device__ __forceinline__ uint32_t rneb(float f) {           // bf16 RNE bits
    uint32_t u = __float_as_uint(f);
    return (u + 0x7FFFu + ((u >> 16) & 1u)) >> 16;
}
__device__ __forceinline__ float bfval(uint32_t b) { return __uint_as_float(b << 16); }

struct Split8 { bf16x8 hi, lo; };
__device__ __forceinline__ Split8 split8(float4 a, float4 b) {
    uint32_t h0=rneb(a.x),h1=rneb(a.y),h2=rneb(a.z),h3=rneb(a.w);
    uint32_t h4=rneb(b.x),h5=rneb(b.y),h6=rneb(b.z),h7=rneb(b.w);
    uint32_t l0=rneb(a.x-bfval(h0)), l1=rneb(a.y-bfval(h1));
    uint32_t l2=rneb(a.z-bfval(h2)), l3=rneb(a.w-bfval(h3));
    uint32_t l4=rneb(b.x-bfval(h4)), l5=rneb(b.y-bfval(h5));
    uint32_t l6=rneb(b.z-bfval(h6)), l7=rneb(b.w-bfval(h7));
    union { bf16x8 v; uint32_t u[4]; } H, L;
    H.u[0]=h0|(h1<<16); H.u[1]=h2|(h3<<16); H.u[2]=h4|(h5<<16); H.u[3]=h6|(h7<<16);
    L.u[0]=l0|(l1<<16); L.u[1]=l2|(l3<<16); L.u[2]=l4|(l5<<16); L.u[3]=l6|(l7<<16);
    Split8 r; r.hi = H.v; r.lo = L.v; return r;
}

// ---- prep: codebook -> fragment-major split-bf16 image (4KB per 16-code chunk) ----
// chunk layout: [B0: 64 lanes x 16B][B1][B2][B3]; lane(j,g)=g*16+j holds code j,
// features g*8..g*8+7; B0/B1 = hi(0..31 / 32..63), B2/B3 = lo.
__global__ __launch_bounds__(256) void vq_prep(const float* __restrict__ cb,
                                               uint8_t* __restrict__ stage,
                                               float* __restrict__ negcn) {
    int t = blockIdx.x * 256 + threadIdx.x;     // 0..32767, one per 8 floats
    int code = t >> 3, oct = t & 7;
    const float4* cp = (const float4*)(cb + (size_t)code * Dn + oct * 8);
    float4 f0 = cp[0], f1 = cp[1];
    Split8 s = split8(f0, f1);
    int j = code & 15, cc = code >> 4;
    uint8_t* base = stage + (size_t)cc * 4096;
    int dsto = (((oct & 3) * 16 + j) << 4) + ((oct & 4) ? 1024 : 0);
    *(bf16x8*)(base + dsto)        = s.hi;
    *(bf16x8*)(base + 2048 + dsto) = s.lo;
    float n = f0.x*f0.x + f0.y*f0.y + f0.z*f0.z + f0.w*f0.w
            + f1.x*f1.x + f1.y*f1.y + f1.z*f1.z + f1.w*f1.w;
    n += __shfl_xor(n, 1); n += __shfl_xor(n, 2); n += __shfl_xor(n, 4);
    if (oct == 0) negcn[code] = -0.5f * n;
}

__global__ void vq_zero(float* __restrict__ loss_acc, int* __restrict__ flag_cnt) {
    *loss_acc = 0.0f; *flag_cnt = 0;
}

// 1024 blocks x 256 thr; 4 waves: (row-tile = w>>1) x (K-half = w&1); 64 rows/wave.
__global__ __launch_bounds__(256, 4) void vq_main(
    const float* __restrict__ x, const uint8_t* __restrict__ stage,
    const float* __restrict__ negcn, const float* __restrict__ cb,
    float* __restrict__ out, float* __restrict__ loss_acc,
    int* __restrict__ flag_cnt, int* __restrict__ flag_rows) {

    __shared__ float sneg[Kn];                       // -0.5|c|^2
    __shared__ float smv1[4][64], smv2[4][64];
    __shared__ int   smk[4][64];
    __shared__ int   sres[128];

    const int tid = threadIdx.x;
    const int lane = tid & 63, w = tid >> 6;
    const int g = lane >> 4, j = lane & 15;
    const int kh = w & 1;                // K-half
    const int cstart = kh * HCHUNK;

    #pragma unroll
    for (int i = 0; i < 16; ++i) sneg[i*256 + tid] = negcn[i*256 + tid];

    // A fragments: 4 sub-tiles of 16 rows (A layout: row=lane&15, k=(lane>>4)*8+e)
    const int rowbase = blockIdx.x * 128 + (w >> 1) * 64;
    bf16x8 ah[4][2], al[4][2];
    #pragma unroll
    for (int t = 0; t < 4; ++t) {
        const float* xr = x + (size_t)(rowbase + t*16 + j) * Dn + g*8;
        Split8 s0 = split8(*(const float4*)xr,        *(const float4*)(xr + 4));
        Split8 s1 = split8(*(const float4*)(xr + 32), *(const float4*)(xr + 36));
        ah[t][0] = s0.hi; al[t][0] = s0.lo;
        ah[t][1] = s1.hi; al[t][1] = s1.lo;
    }

    float b1[16], b2[16]; int bch[16];
    #pragma unroll
    for (int s = 0; s < 16; ++s) { b1[s] = -3.4e38f; b2[s] = -3.4e38f; bch[s] = 0; }

    // 4-deep register prefetch of B fragments straight from L2 (no LDS, no barriers)
    const uint8_t* sp = stage + (lane << 4);
    bf16x8 Bf[4][4];
    #pragma unroll
    for (int p = 0; p < 4; ++p) {
        const uint8_t* bbp = sp + ((size_t)(cstart + p) << 12);
        Bf[p][0] = *(const bf16x8*)(bbp);
        Bf[p][1] = *(const bf16x8*)(bbp + 1024);
        Bf[p][2] = *(const bf16x8*)(bbp + 2048);
        Bf[p][3] = *(const bf16x8*)(bbp + 3072);
    }
    __syncthreads();     // sneg visible

#define CHUNK_BODY(P, C, RELOAD)                                              \
    {                                                                         \
        const int c_ = (C);                                                   \
        bf16x8 B0 = Bf[P][0], B1 = Bf[P][1], B2 = Bf[P][2], B3 = Bf[P][3];    \
        float nc = sneg[(c_ << 4) + j];                                       \
        f32x4 a0 = {nc,nc,nc,nc}, a1 = {nc,nc,nc,nc};                         \
        f32x4 a2 = {nc,nc,nc,nc}, a3 = {nc,nc,nc,nc};                         \
        a0 = __builtin_amdgcn_mfma_f32_16x16x32_bf16(ah[0][0], B0, a0, 0,0,0);\
        a1 = __builtin_amdgcn_mfma_f32_16x16x32_bf16(ah[1][0], B0, a1, 0,0,0);\
        a2 = __builtin_amdgcn_mfma_f32_16x16x32_bf16(ah[2][0], B0, a2, 0,0,0);\
        a3 = __builtin_amdgcn_mfma_f32_16x16x32_bf16(ah[3][0], B0, a3, 0,0,0);\
        a0 = __builtin_amdgcn_mfma_f32_16x16x32_bf16(ah[0][1], B1, a0, 0,0,0);\
        a1 = __builtin_amdgcn_mfma_f32_16x16x32_bf16(ah[1][1], B1, a1, 0,0,0);\
        a2 = __builtin_amdgcn_mfma_f32_16x16x32_bf16(ah[2][1], B1, a2, 0,0,0);\
        a3 = __builtin_amdgcn_mfma_f32_16x16x32_bf16(ah[3][1], B1, a3, 0,0,0);\
        a0 = __builtin_amdgcn_mfma_f32_16x16x32_bf16(al[0][0], B0, a0, 0,0,0);\
        a1 = __builtin_amdgcn_mfma_f32_16x16x32_bf16(al[1][0], B0, a1, 0,0,0);\
        a2 = __builtin_amdgcn_mfma_f32_16x16x32_bf16(al[2][0], B0, a2, 0,0,0);\
        a3 = __builtin_amdgcn_mfma_f32_16x16x32_bf16(al[3][0], B0, a3, 0,0,0);\
        a0 = __builtin_amdgcn_mfma_f32_16x16x32_bf16(al[0][1], B1, a0, 0,0,0);\
        a1 = __builtin_amdgcn_mfma_f32_16x16x32_bf16(al[1][1], B1, a1, 0,0,0);\
        a2 = __builtin_amdgcn_mfma_f32_16x16x32_bf16(al[2][1], B1, a2, 0,0,0);\
        a3 = __builtin_amdgcn_mfma_f32_16x16x32_bf16(al[3][1], B1, a3, 0,0,0);\
        a0 = __builtin_amdgcn_mfma_f32_16x16x32_bf16(ah[0][0], B2, a0, 0,0,0);\
        a1 = __builtin_amdgcn_mfma_f32_16x16x32_bf16(ah[1][0], B2, a1, 0,0,0);\
        a2 = __builtin_amdgcn_mfma_f32_16x16x32_bf16(ah[2][0], B2, a2, 0,0,0);\
        a3 = __builtin_amdgcn_mfma_f32_16x16x32_bf16(ah[3][0], B2, a3, 0,0,0);\
        a0 = __builtin_amdgcn_mfma_f32_16x16x32_bf16(ah[0][1], B3, a0, 0,0,0);\
        a1 = __builtin_amdgcn_mfma_f32_16x16x32_bf16(ah[1][1], B3, a1, 0,0,0);\
        a2 = __builtin_amdgcn_mfma_f32_16x16x32_bf16(ah[2][1], B3, a2, 0,0,0);\
        a3 = __builtin_amdgcn_mfma_f32_16x16x32_bf16(ah[3][1], B3, a3, 0,0,0);\
        if (RELOAD) {   /* prefetch chunk c_+4 into this slot */              \
            const uint8_t* nb = sp + ((size_t)(c_ + 4) << 12);                \
            Bf[P][0] = *(const bf16x8*)(nb);                                  \
            Bf[P][1] = *(const bf16x8*)(nb + 1024);                           \
            Bf[P][2] = *(const bf16x8*)(nb + 2048);                           \
            Bf[P][3] = *(const bf16x8*)(nb + 3072);                           \
        }                                                                     \
        f32x4 aa[4] = {a0, a1, a2, a3};                                       \
        _Pragma("unroll")                                                     \
        for (int t = 0; t < 4; ++t) {                                         \
            _Pragma("unroll")                                                 \
            for (int q = 0; q < 4; ++q) {                                     \
                int s = t*4 + q;                                              \
                float v = aa[t][q], ob = b1[s];                               \
                b2[s]  = fmaxf(fminf(v, ob), b2[s]);                          \
                bch[s] = (v > ob) ? c_ : bch[s];                              \
                b1[s]  = fmaxf(v, ob);                                        \
            }                                                                 \
        }                                                                     \
    }

    #pragma unroll 1
    for (int c4 = cstart; c4 < cstart + HCHUNK - 4; c4 += 4) {
        CHUNK_BODY(0, c4 + 0, true)
        CHUNK_BODY(1, c4 + 1, true)
        CHUNK_BODY(2, c4 + 2, true)
        CHUNK_BODY(3, c4 + 3, true)
    }
    CHUNK_BODY(0, cstart + HCHUNK - 4, false)
    CHUNK_BODY(1, cstart + HCHUNK - 3, false)
    CHUNK_BODY(2, cstart + HCHUNK - 2, false)
    CHUNK_BODY(3, cstart + HCHUNK - 1, false)
#undef CHUNK_BODY

    // per-row merge across the 16 code-lanes (D layout: row=(lane>>4)*4+q, col=lane&15)
    #pragma unroll
    for (int s = 0; s < 16; ++s) {
        float v1 = b1[s], v2 = b2[s];
        int kk = bch[s] * 16 + j;
        #pragma unroll
        for (int m = 1; m < 16; m <<= 1) {
            float p1 = __shfl_xor(v1, m);
            float p2 = __shfl_xor(v2, m);
            int pk = __shfl_xor(kk, m);
            v2 = fmaxf(fmaxf(v2, p2), fminf(v1, p1));
            bool take = (p1 > v1) || ((p1 == v1) && (pk < kk));
            v1 = take ? p1 : v1;
            kk = take ? pk : kk;
        }
        if (j == 0) {
            int row = (s >> 2)*16 + g*4 + (s & 3);   // 0..63 within wave
            smv1[w][row] = v1; smv2[w][row] = v2; smk[w][row] = kk;
        }
    }
    __syncthreads();

    // cross-K-half merge: row r of block -> waves (rt*2) and (rt*2+1).
    // Disjoint k-ranges, half 0 has lower k: on tie keep half 0 (first occurrence).
    if (tid < 128) {
        int rt = tid >> 6, r = tid & 63;
        int wa = rt * 2, wb = wa + 1;
        float v1a = smv1[wa][r], v2a = smv2[wa][r];
        float v1b = smv1[wb][r], v2b = smv2[wb][r];
        int   ka  = smk[wa][r],  kb  = smk[wb][r];
        bool take = v1b > v1a;
        float m1 = take ? v1b : v1a;
        int   kk = take ? kb  : ka;
        float m2 = fmaxf(fmaxf(v2a, v2b), fminf(v1a, v1b));
        int flag = ((m1 - m2) < TAU_S) ? (int)0x80000000 : 0;
        sres[tid] = kk | flag;
    }
    __syncthreads();

    // epilogue: fully coalesced; f enumerates (row, float4) pairs; 128 rows/block
    float ls = 0.f;
    const size_t blockrow = (size_t)blockIdx.x * 128;
    #pragma unroll 1
    for (int it = 0; it < 8; ++it) {
        int f = it * 256 + tid;
        int r = f >> 4, q = f & 15;
        int pk = sres[r];
        int idx = pk & 0x7FFFFFFF;
        bool flagged = pk < 0;
        size_t grow = blockrow + r;
        float4 xx = ((const float4*)(x + grow * Dn))[q];
        float4 qq = ((const float4*)(cb + (size_t)idx * Dn))[q];
        float dx = qq.x - xx.x, dy = qq.y - xx.y, dz = qq.z - xx.z, dw = qq.w - xx.w;
        float4 o; o.x = xx.x + dx; o.y = xx.y + dy; o.z = xx.z + dz; o.w = xx.w + dw;
        ((float4*)(out + grow * Dn))[q] = o;
        if (flagged) {
            if (q == 0) { int p = atomicAdd(flag_cnt, 1); flag_rows[p] = (int)grow; }
        } else {
            ls = fmaf(dx, dx, ls); ls = fmaf(dy, dy, ls);
            ls = fmaf(dz, dz, ls); ls = fmaf(dw, dw, ls);
        }
    }
    #pragma unroll
    for (int m = 1; m < 64; m <<= 1) ls += __shfl_xor(ls, m);
    if (lane == 0) atomicAdd(loss_acc, ls);
}

// fp64 full rescan of flagged rows, 4 rows per block-iteration (codebook read shared).
__global__ __launch_bounds__(256) void vq_cleanup(
    const float* __restrict__ x, const float* __restrict__ cb,
    const int* __restrict__ flag_cnt, const int* __restrict__ flag_rows,
    float* __restrict__ out, float* __restrict__ loss_acc) {
    __shared__ double sxd[4][Dn];
    __shared__ double swb[4][4];
    __shared__ int    swi[4][4];
    const int tid = threadIdx.x;
    const int n = *flag_cnt;

    for (int it = blockIdx.x; it * 4 < n; it += gridDim.x) {
        const int base = it * 4;
        const int nr = min(4, n - base);
        __syncthreads();   // protect sxd/swb from previous iteration readers
        {
            int rr = tid >> 6, e = tid & 63;
            int row = flag_rows[base + ((rr < nr) ? rr : 0)];
            sxd[rr][e] = (double)x[(size_t)row * Dn + e];
        }
        __syncthreads();

        double best[4]; int bidx[4];
        #pragma unroll
        for (int r2 = 0; r2 < 4; ++r2) { best[r2] = 1.0e300; bidx[r2] = 0x7FFFFFFF; }

        #pragma unroll 1
        for (int i = 0; i < Kn / 256; ++i) {          // 16 codes per thread
            const int k = i * 256 + tid;
            const float* c4 = cb + (size_t)k * Dn;
            double cn = 0.0;
            double d0 = 0.0, d1 = 0.0, d2 = 0.0, d3 = 0.0;
            #pragma unroll 8
            for (int e = 0; e < Dn; ++e) {
                double ce = (double)c4[e];
                cn = fma(ce, ce, cn);
                d0 = fma(ce, sxd[0][e], d0);
                d1 = fma(ce, sxd[1][e], d1);
                d2 = fma(ce, sxd[2][e], d2);
                d3 = fma(ce, sxd[3][e], d3);
            }
            double dd[4] = { cn - 2.0*d0, cn - 2.0*d1, cn - 2.0*d2, cn - 2.0*d3 };
            #pragma unroll
            for (int r2 = 0; r2 < 4; ++r2)
                if (dd[r2] < best[r2] || (dd[r2] == best[r2] && k < bidx[r2])) {
                    best[r2] = dd[r2]; bidx[r2] = k;
                }
        }
        // wave argmin then cross-wave merge (first-occurrence ties)
        #pragma unroll
        for (int r2 = 0; r2 < 4; ++r2) {
            double bb = best[r2]; int bi = bidx[r2];
            #pragma unroll
            for (int m = 1; m < 64; m <<= 1) {
                double pb = __shfl_xor(bb, m);
                int    pi = __shfl_xor(bi, m);
                if (pb < bb || (pb == bb && pi < bi)) { bb = pb; bi = pi; }
            }
            if ((tid & 63) == 0) { swb[r2][tid >> 6] = bb; swi[r2][tid >> 6] = bi; }
        }
        __syncthreads();
        if (tid < 4) {
            double fb = swb[tid][0]; int fi = swi[tid][0];
            #pragma unroll
            for (int wv = 1; wv < 4; ++wv) {
                double pb = swb[tid][wv]; int pi = swi[tid][wv];
                if (pb < fb || (pb == fb && pi < fi)) { fb = pb; fi = pi; }
            }
            swi[tid][0] = fi;
        }
        __syncthreads();

        if (tid < 64) {
            int r2 = tid >> 4, q = tid & 15;
            if (r2 < nr) {
                int row = flag_rows[base + r2];
                int fi  = swi[r2][0];
                float4 xx = ((const float4*)(x + (size_t)row * Dn))[q];
                float4 qq = ((const float4*)(cb + (size_t)fi * Dn))[q];
                float dx = qq.x - xx.x, dy = qq.y - xx.y, dz = qq.z - xx.z, dw = qq.w - xx.w;
                float4 o; o.x = xx.x + dx; o.y = xx.y + dy; o.z = xx.z + dz; o.w = xx.w + dw;
                ((float4*)(out + (size_t)row * Dn))[q] = o;
                float ls = dx*dx + dy*dy + dz*dz + dw*dw;
                ls += __shfl_xor(ls, 1); ls += __shfl_xor(ls, 2);
                ls += __shfl_xor(ls, 4); ls += __shfl_xor(ls, 8);
                if (q == 0) atomicAdd(loss_acc, ls);
            }
        }
    }
}

__global__ void vq_final(float* __restrict__ loss_acc) {
    *loss_acc = *loss_acc * (1.25f / (float)(Bn * Dn));
}

extern "C" void kernel_launch(void* const* d_in, const int* in_sizes, int n_in,
                              void* d_out, int out_size, void* d_ws, size_t ws_size,
                              hipStream_t stream) {
    const float* x  = (const float*)d_in[0];
    const float* cb = (const float*)d_in[1];
    float* out  = (float*)d_out;
    float* loss = out + (size_t)Bn * Dn;

    // ws layout: [negcn 16KB][stage 1MB][flag_cnt 4B][flag_rows 512KB]
    uint8_t* wsb = (uint8_t*)d_ws;
    float*   negcn     = (float*)wsb;
    uint8_t* stage     = wsb + 16384;
    int*     flag_cnt  = (int*)(wsb + 16384 + (size_t)NCHUNK * 4096);
    int*     flag_rows = flag_cnt + 1;

    vq_prep<<<128, 256, 0, stream>>>(cb, stage, negcn);
    vq_zero<<<1, 1, 0, stream>>>(loss, flag_cnt);
    vq_main<<<Bn / 128, 256, 0, stream>>>(x, stage, negcn, cb, out, loss, flag_cnt, flag_rows);
    vq_cleanup<<<512, 256, 0, stream>>>(x, cb, flag_cnt, flag_rows, out, loss);
    vq_final<<<1, 1, 0, stream>>>(loss);
}

// Round 8
// 764.751 us; speedup vs baseline: 2.2983x; 2.2983x over previous
//
#include <hip/hip_runtime.h>
#include <stdint.h>

// VQ: B=131072 rows, K=4096 codes, D=64, fp32 in/out.
// out = [B*D floats quantized_st][1 float loss]
//
// bf16 split-precision MFMA distance search (3-product exact-split, score
// error <~1e-3), per-row top-2 tracking, fp64 full rescan of near-tie rows.
// K-loop: B fragments loaded directly from L2-resident stage image into VGPRs,
// 2-deep register pipeline, no barriers in the loop. K-SPLIT: each wave scans
// half the codebook for 64 rows (waves 2w,2w+1 share rows, disjoint K halves),
// merged via LDS afterward. launch_bounds(256,3): ~170 VGPR cap fits the
// ~160-reg live set (r7 lesson: (256,4)=128 cap forced total spill).
constexpr int Bn = 131072, Kn = 4096, Dn = 64;
constexpr int NCHUNK = 256;          // K / 16 codes per chunk
constexpr int HCHUNK = 128;          // chunks per K-half
constexpr float TAU_S = 0.008f;      // score-gap flag threshold (~8x error bound)

typedef short bf16x8 __attribute__((ext_vector_type(8)));
typedef float f32x4  __attribute__((ext_vector_type(4)));

__device__ __forceinline__ uint32_t rneb(float f) {           // bf16 RNE bits
    uint32_t u = __float_as_uint(f);
    return (u + 0x7FFFu + ((u >> 16) & 1u)) >> 16;
}
__device__ __forceinline__ float bfval(uint32_t b) { return __uint_as_float(b << 16); }

struct Split8 { bf16x8 hi, lo; };
__device__ __forceinline__ Split8 split8(float4 a, float4 b) {
    uint32_t h0=rneb(a.x),h1=rneb(a.y),h2=rneb(a.z),h3=rneb(a.w);
    uint32_t h4=rneb(b.x),h5=rneb(b.y),h6=rneb(b.z),h7=rneb(b.w);
    uint32_t l0=rneb(a.x-bfval(h0)), l1=rneb(a.y-bfval(h1));
    uint32_t l2=rneb(a.z-bfval(h2)), l3=rneb(a.w-bfval(h3));
    uint32_t l4=rneb(b.x-bfval(h4)), l5=rneb(b.y-bfval(h5));
    uint32_t l6=rneb(b.z-bfval(h6)), l7=rneb(b.w-bfval(h7));
    union { bf16x8 v; uint32_t u[4]; } H, L;
    H.u[0]=h0|(h1<<16); H.u[1]=h2|(h3<<16); H.u[2]=h4|(h5<<16); H.u[3]=h6|(h7<<16);
    L.u[0]=l0|(l1<<16); L.u[1]=l2|(l3<<16); L.u[2]=l4|(l5<<16); L.u[3]=l6|(l7<<16);
    Split8 r; r.hi = H.v; r.lo = L.v; return r;
}

// ---- prep: codebook -> fragment-major split-bf16 image (4KB per 16-code chunk) ----
// chunk layout: [B0: 64 lanes x 16B][B1][B2][B3]; lane(j,g)=g*16+j holds code j,
// features g*8..g*8+7; B0/B1 = hi(0..31 / 32..63), B2/B3 = lo.
__global__ __launch_bounds__(256) void vq_prep(const float* __restrict__ cb,
                                               uint8_t* __restrict__ stage,
                                               float* __restrict__ negcn) {
    int t = blockIdx.x * 256 + threadIdx.x;     // 0..32767, one per 8 floats
    int code = t >> 3, oct = t & 7;
    const float4* cp = (const float4*)(cb + (size_t)code * Dn + oct * 8);
    float4 f0 = cp[0], f1 = cp[1];
    Split8 s = split8(f0, f1);
    int j = code & 15, cc = code >> 4;
    uint8_t* base = stage + (size_t)cc * 4096;
    int dsto = (((oct & 3) * 16 + j) << 4) + ((oct & 4) ? 1024 : 0);
    *(bf16x8*)(base + dsto)        = s.hi;
    *(bf16x8*)(base + 2048 + dsto) = s.lo;
    float n = f0.x*f0.x + f0.y*f0.y + f0.z*f0.z + f0.w*f0.w
            + f1.x*f1.x + f1.y*f1.y + f1.z*f1.z + f1.w*f1.w;
    n += __shfl_xor(n, 1); n += __shfl_xor(n, 2); n += __shfl_xor(n, 4);
    if (oct == 0) negcn[code] = -0.5f * n;
}

__global__ void vq_zero(float* __restrict__ loss_acc, int* __restrict__ flag_cnt) {
    *loss_acc = 0.0f; *flag_cnt = 0;
}

// 1024 blocks x 256 thr; 4 waves: (row-tile = w>>1) x (K-half = w&1); 64 rows/wave.
__global__ __launch_bounds__(256, 3) void vq_main(
    const float* __restrict__ x, const uint8_t* __restrict__ stage,
    const float* __restrict__ negcn, const float* __restrict__ cb,
    float* __restrict__ out, float* __restrict__ loss_acc,
    int* __restrict__ flag_cnt, int* __restrict__ flag_rows) {

    __shared__ float sneg[Kn];                       // -0.5|c|^2
    __shared__ float smv1[4][64], smv2[4][64];
    __shared__ int   smk[4][64];
    __shared__ int   sres[128];

    const int tid = threadIdx.x;
    const int lane = tid & 63, w = tid >> 6;
    const int g = lane >> 4, j = lane & 15;
    const int kh = w & 1;                // K-half
    const int cstart = kh * HCHUNK;

    #pragma unroll
    for (int i = 0; i < 16; ++i) sneg[i*256 + tid] = negcn[i*256 + tid];

    // A fragments: 4 sub-tiles of 16 rows (A layout: row=lane&15, k=(lane>>4)*8+e)
    const int rowbase = blockIdx.x * 128 + (w >> 1) * 64;
    bf16x8 ah[4][2], al[4][2];
    #pragma unroll
    for (int t = 0; t < 4; ++t) {
        const float* xr = x + (size_t)(rowbase + t*16 + j) * Dn + g*8;
        Split8 s0 = split8(*(const float4*)xr,        *(const float4*)(xr + 4));
        Split8 s1 = split8(*(const float4*)(xr + 32), *(const float4*)(xr + 36));
        ah[t][0] = s0.hi; al[t][0] = s0.lo;
        ah[t][1] = s1.hi; al[t][1] = s1.lo;
    }

    float b1[16], b2[16]; int bch[16];
    #pragma unroll
    for (int s = 0; s < 16; ++s) { b1[s] = -3.4e38f; b2[s] = -3.4e38f; bch[s] = 0; }

    // 2-deep register prefetch of B fragments straight from L2 (no LDS, no barriers)
    const uint8_t* sp = stage + (lane << 4);
    bf16x8 Bf[2][4];
    #pragma unroll
    for (int p = 0; p < 2; ++p) {
        const uint8_t* bbp = sp + ((size_t)(cstart + p) << 12);
        Bf[p][0] = *(const bf16x8*)(bbp);
        Bf[p][1] = *(const bf16x8*)(bbp + 1024);
        Bf[p][2] = *(const bf16x8*)(bbp + 2048);
        Bf[p][3] = *(const bf16x8*)(bbp + 3072);
    }
    __syncthreads();     // sneg visible

#define CHUNK_BODY(P, C, RELOAD)                                              \
    {                                                                         \
        const int c_ = (C);                                                   \
        bf16x8 B0 = Bf[P][0], B1 = Bf[P][1], B2 = Bf[P][2], B3 = Bf[P][3];    \
        float nc = sneg[(c_ << 4) + j];                                       \
        f32x4 a0 = {nc,nc,nc,nc}, a1 = {nc,nc,nc,nc};                         \
        f32x4 a2 = {nc,nc,nc,nc}, a3 = {nc,nc,nc,nc};                         \
        a0 = __builtin_amdgcn_mfma_f32_16x16x32_bf16(ah[0][0], B0, a0, 0,0,0);\
        a1 = __builtin_amdgcn_mfma_f32_16x16x32_bf16(ah[1][0], B0, a1, 0,0,0);\
        a2 = __builtin_amdgcn_mfma_f32_16x16x32_bf16(ah[2][0], B0, a2, 0,0,0);\
        a3 = __builtin_amdgcn_mfma_f32_16x16x32_bf16(ah[3][0], B0, a3, 0,0,0);\
        a0 = __builtin_amdgcn_mfma_f32_16x16x32_bf16(ah[0][1], B1, a0, 0,0,0);\
        a1 = __builtin_amdgcn_mfma_f32_16x16x32_bf16(ah[1][1], B1, a1, 0,0,0);\
        a2 = __builtin_amdgcn_mfma_f32_16x16x32_bf16(ah[2][1], B1, a2, 0,0,0);\
        a3 = __builtin_amdgcn_mfma_f32_16x16x32_bf16(ah[3][1], B1, a3, 0,0,0);\
        a0 = __builtin_amdgcn_mfma_f32_16x16x32_bf16(al[0][0], B0, a0, 0,0,0);\
        a1 = __builtin_amdgcn_mfma_f32_16x16x32_bf16(al[1][0], B0, a1, 0,0,0);\
        a2 = __builtin_amdgcn_mfma_f32_16x16x32_bf16(al[2][0], B0, a2, 0,0,0);\
        a3 = __builtin_amdgcn_mfma_f32_16x16x32_bf16(al[3][0], B0, a3, 0,0,0);\
        a0 = __builtin_amdgcn_mfma_f32_16x16x32_bf16(al[0][1], B1, a0, 0,0,0);\
        a1 = __builtin_amdgcn_mfma_f32_16x16x32_bf16(al[1][1], B1, a1, 0,0,0);\
        a2 = __builtin_amdgcn_mfma_f32_16x16x32_bf16(al[2][1], B1, a2, 0,0,0);\
        a3 = __builtin_amdgcn_mfma_f32_16x16x32_bf16(al[3][1], B1, a3, 0,0,0);\
        a0 = __builtin_amdgcn_mfma_f32_16x16x32_bf16(ah[0][0], B2, a0, 0,0,0);\
        a1 = __builtin_amdgcn_mfma_f32_16x16x32_bf16(ah[1][0], B2, a1, 0,0,0);\
        a2 = __builtin_amdgcn_mfma_f32_16x16x32_bf16(ah[2][0], B2, a2, 0,0,0);\
        a3 = __builtin_amdgcn_mfma_f32_16x16x32_bf16(ah[3][0], B2, a3, 0,0,0);\
        a0 = __builtin_amdgcn_mfma_f32_16x16x32_bf16(ah[0][1], B3, a0, 0,0,0);\
        a1 = __builtin_amdgcn_mfma_f32_16x16x32_bf16(ah[1][1], B3, a1, 0,0,0);\
        a2 = __builtin_amdgcn_mfma_f32_16x16x32_bf16(ah[2][1], B3, a2, 0,0,0);\
        a3 = __builtin_amdgcn_mfma_f32_16x16x32_bf16(ah[3][1], B3, a3, 0,0,0);\
        if (RELOAD) {   /* prefetch chunk c_+2 into this slot */              \
            const uint8_t* nb = sp + ((size_t)(c_ + 2) << 12);                \
            Bf[P][0] = *(const bf16x8*)(nb);                                  \
            Bf[P][1] = *(const bf16x8*)(nb + 1024);                           \
            Bf[P][2] = *(const bf16x8*)(nb + 2048);                           \
            Bf[P][3] = *(const bf16x8*)(nb + 3072);                           \
        }                                                                     \
        _Pragma("unroll")                                                     \
        for (int q = 0; q < 4; ++q) {                                         \
            float v = a0[q], ob = b1[q];                                      \
            b2[q]   = fmaxf(fminf(v, ob), b2[q]);                             \
            bch[q]  = (v > ob) ? c_ : bch[q];                                 \
            b1[q]   = fmaxf(v, ob);                                           \
        }                                                                     \
        _Pragma("unroll")                                                     \
        for (int q = 0; q < 4; ++q) {                                         \
            float v = a1[q], ob = b1[4+q];                                    \
            b2[4+q]  = fmaxf(fminf(v, ob), b2[4+q]);                          \
            bch[4+q] = (v > ob) ? c_ : bch[4+q];                              \
            b1[4+q]  = fmaxf(v, ob);                                          \
        }                                                                     \
        _Pragma("unroll")                                                     \
        for (int q = 0; q < 4; ++q) {                                         \
            float v = a2[q], ob = b1[8+q];                                    \
            b2[8+q]  = fmaxf(fminf(v, ob), b2[8+q]);                          \
            bch[8+q] = (v > ob) ? c_ : bch[8+q];                              \
            b1[8+q]  = fmaxf(v, ob);                                          \
        }                                                                     \
        _Pragma("unroll")                                                     \
        for (int q = 0; q < 4; ++q) {                                         \
            float v = a3[q], ob = b1[12+q];                                   \
            b2[12+q]  = fmaxf(fminf(v, ob), b2[12+q]);                        \
            bch[12+q] = (v > ob) ? c_ : bch[12+q];                            \
            b1[12+q]  = fmaxf(v, ob);                                         \
        }                                                                     \
    }

    #pragma unroll 1
    for (int c4 = cstart; c4 < cstart + HCHUNK - 2; c4 += 2) {
        CHUNK_BODY(0, c4 + 0, true)
        CHUNK_BODY(1, c4 + 1, true)
    }
    CHUNK_BODY(0, cstart + HCHUNK - 2, false)
    CHUNK_BODY(1, cstart + HCHUNK - 1, false)
#undef CHUNK_BODY

    // per-row merge across the 16 code-lanes (D layout: row=(lane>>4)*4+q, col=lane&15)
    #pragma unroll
    for (int s = 0; s < 16; ++s) {
        float v1 = b1[s], v2 = b2[s];
        int kk = bch[s] * 16 + j;
        #pragma unroll
        for (int m = 1; m < 16; m <<= 1) {
            float p1 = __shfl_xor(v1, m);
            float p2 = __shfl_xor(v2, m);
            int pk = __shfl_xor(kk, m);
            v2 = fmaxf(fmaxf(v2, p2), fminf(v1, p1));
            bool take = (p1 > v1) || ((p1 == v1) && (pk < kk));
            v1 = take ? p1 : v1;
            kk = take ? pk : kk;
        }
        if (j == 0) {
            int row = (s >> 2)*16 + g*4 + (s & 3);   // 0..63 within wave
            smv1[w][row] = v1; smv2[w][row] = v2; smk[w][row] = kk;
        }
    }
    __syncthreads();

    // cross-K-half merge: row r of block -> waves (rt*2) and (rt*2+1).
    // Disjoint k-ranges, half 0 has lower k: on tie keep half 0 (first occurrence).
    if (tid < 128) {
        int rt = tid >> 6, r = tid & 63;
        int wa = rt * 2, wb = wa + 1;
        float v1a = smv1[wa][r], v2a = smv2[wa][r];
        float v1b = smv1[wb][r], v2b = smv2[wb][r];
        int   ka  = smk[wa][r],  kb  = smk[wb][r];
        bool take = v1b > v1a;
        float m1 = take ? v1b : v1a;
        int   kk = take ? kb  : ka;
        float m2 = fmaxf(fmaxf(v2a, v2b), fminf(v1a, v1b));
        int flag = ((m1 - m2) < TAU_S) ? (int)0x80000000 : 0;
        sres[tid] = kk | flag;
    }
    __syncthreads();

    // epilogue: fully coalesced; f enumerates (row, float4) pairs; 128 rows/block
    float ls = 0.f;
    const size_t blockrow = (size_t)blockIdx.x * 128;
    #pragma unroll 1
    for (int it = 0; it < 8; ++it) {
        int f = it * 256 + tid;
        int r = f >> 4, q = f & 15;
        int pk = sres[r];
        int idx = pk & 0x7FFFFFFF;
        bool flagged = pk < 0;
        size_t grow = blockrow + r;
        float4 xx = ((const float4*)(x + grow * Dn))[q];
        float4 qq = ((const float4*)(cb + (size_t)idx * Dn))[q];
        float dx = qq.x - xx.x, dy = qq.y - xx.y, dz = qq.z - xx.z, dw = qq.w - xx.w;
        float4 o; o.x = xx.x + dx; o.y = xx.y + dy; o.z = xx.z + dz; o.w = xx.w + dw;
        ((float4*)(out + grow * Dn))[q] = o;
        if (flagged) {
            if (q == 0) { int p = atomicAdd(flag_cnt, 1); flag_rows[p] = (int)grow; }
        } else {
            ls = fmaf(dx, dx, ls); ls = fmaf(dy, dy, ls);
            ls = fmaf(dz, dz, ls); ls = fmaf(dw, dw, ls);
        }
    }
    #pragma unroll
    for (int m = 1; m < 64; m <<= 1) ls += __shfl_xor(ls, m);
    if (lane == 0) atomicAdd(loss_acc, ls);
}

// fp64 full rescan of flagged rows, 4 rows per block-iteration (codebook read shared).
__global__ __launch_bounds__(256) void vq_cleanup(
    const float* __restrict__ x, const float* __restrict__ cb,
    const int* __restrict__ flag_cnt, const int* __restrict__ flag_rows,
    float* __restrict__ out, float* __restrict__ loss_acc) {
    __shared__ double sxd[4][Dn];
    __shared__ double swb[4][4];
    __shared__ int    swi[4][4];
    const int tid = threadIdx.x;
    const int n = *flag_cnt;

    for (int it = blockIdx.x; it * 4 < n; it += gridDim.x) {
        const int base = it * 4;
        const int nr = min(4, n - base);
        __syncthreads();   // protect sxd/swb from previous iteration readers
        {
            int rr = tid >> 6, e = tid & 63;
            int row = flag_rows[base + ((rr < nr) ? rr : 0)];
            sxd[rr][e] = (double)x[(size_t)row * Dn + e];
        }
        __syncthreads();

        double best[4]; int bidx[4];
        #pragma unroll
        for (int r2 = 0; r2 < 4; ++r2) { best[r2] = 1.0e300; bidx[r2] = 0x7FFFFFFF; }

        #pragma unroll 1
        for (int i = 0; i < Kn / 256; ++i) {          // 16 codes per thread
            const int k = i * 256 + tid;
            const float* c4 = cb + (size_t)k * Dn;
            double cn = 0.0;
            double d0 = 0.0, d1 = 0.0, d2 = 0.0, d3 = 0.0;
            #pragma unroll 8
            for (int e = 0; e < Dn; ++e) {
                double ce = (double)c4[e];
                cn = fma(ce, ce, cn);
                d0 = fma(ce, sxd[0][e], d0);
                d1 = fma(ce, sxd[1][e], d1);
                d2 = fma(ce, sxd[2][e], d2);
                d3 = fma(ce, sxd[3][e], d3);
            }
            double dd[4] = { cn - 2.0*d0, cn - 2.0*d1, cn - 2.0*d2, cn - 2.0*d3 };
            #pragma unroll
            for (int r2 = 0; r2 < 4; ++r2)
                if (dd[r2] < best[r2] || (dd[r2] == best[r2] && k < bidx[r2])) {
                    best[r2] = dd[r2]; bidx[r2] = k;
                }
        }
        // wave argmin then cross-wave merge (first-occurrence ties)
        #pragma unroll
        for (int r2 = 0; r2 < 4; ++r2) {
            double bb = best[r2]; int bi = bidx[r2];
            #pragma unroll
            for (int m = 1; m < 64; m <<= 1) {
                double pb = __shfl_xor(bb, m);
                int    pi = __shfl_xor(bi, m);
                if (pb < bb || (pb == bb && pi < bi)) { bb = pb; bi = pi; }
            }
            if ((tid & 63) == 0) { swb[r2][tid >> 6] = bb; swi[r2][tid >> 6] = bi; }
        }
        __syncthreads();
        if (tid < 4) {
            double fb = swb[tid][0]; int fi = swi[tid][0];
            #pragma unroll
            for (int wv = 1; wv < 4; ++wv) {
                double pb = swb[tid][wv]; int pi = swi[tid][wv];
                if (pb < fb || (pb == fb && pi < fi)) { fb = pb; fi = pi; }
            }
            swi[tid][0] = fi;
        }
        __syncthreads();

        if (tid < 64) {
            int r2 = tid >> 4, q = tid & 15;
            if (r2 < nr) {
                int row = flag_rows[base + r2];
                int fi  = swi[r2][0];
                float4 xx = ((const float4*)(x + (size_t)row * Dn))[q];
                float4 qq = ((const float4*)(cb + (size_t)fi * Dn))[q];
                float dx = qq.x - xx.x, dy = qq.y - xx.y, dz = qq.z - xx.z, dw = qq.w - xx.w;
                float4 o; o.x = xx.x + dx; o.y = xx.y + dy; o.z = xx.z + dz; o.w = xx.w + dw;
                ((float4*)(out + (size_t)row * Dn))[q] = o;
                float ls = dx*dx + dy*dy + dz*dz + dw*dw;
                ls += __shfl_xor(ls, 1); ls += __shfl_xor(ls, 2);
                ls += __shfl_xor(ls, 4); ls += __shfl_xor(ls, 8);
                if (q == 0) atomicAdd(loss_acc, ls);
            }
        }
    }
}

__global__ void vq_final(float* __restrict__ loss_acc) {
    *loss_acc = *loss_acc * (1.25f / (float)(Bn * Dn));
}

extern "C" void kernel_launch(void* const* d_in, const int* in_sizes, int n_in,
                              void* d_out, int out_size, void* d_ws, size_t ws_size,
                              hipStream_t stream) {
    const float* x  = (const float*)d_in[0];
    const float* cb = (const float*)d_in[1];
    float* out  = (float*)d_out;
    float* loss = out + (size_t)Bn * Dn;

    // ws layout: [negcn 16KB][stage 1MB][flag_cnt 4B][flag_rows 512KB]
    uint8_t* wsb = (uint8_t*)d_ws;
    float*   negcn     = (float*)wsb;
    uint8_t* stage     = wsb + 16384;
    int*     flag_cnt  = (int*)(wsb + 16384 + (size_t)NCHUNK * 4096);
    int*     flag_rows = flag_cnt + 1;

    vq_prep<<<128, 256, 0, stream>>>(cb, stage, negcn);
    vq_zero<<<1, 1, 0, stream>>>(loss, flag_cnt);
    vq_main<<<Bn / 128, 256, 0, stream>>>(x, stage, negcn, cb, out, loss, flag_cnt, flag_rows);
    vq_cleanup<<<512, 256, 0, stream>>>(x, cb, flag_cnt, flag_rows, out, loss);
    vq_final<<<1, 1, 0, stream>>>(loss);
}

// Round 9
// 263.625 us; speedup vs baseline: 6.6671x; 2.9009x over previous
//
#include <hip/hip_runtime.h>
#include <stdint.h>

// VQ: B=131072 rows, K=4096 codes, D=64, fp32 in/out.
// out = [B*D floats quantized_st][1 float loss]
//
// bf16 split-precision MFMA distance search (3-product exact-split), top-2
// tracking with the CHUNK INDEX PACKED into the score's low mantissa byte
// (b1/b2 only, no index array -> med3+max update, small live set), fp64
// rescan of rows whose packed score gap < TAU (covers split error + packing
// perturbation). K-SPLIT: waves 2t,2t+1 share 64 rows, scan disjoint K halves;
// 1024 blocks, launch_bounds(256,3) -> 3 waves/SIMD with ~159-reg live set.
constexpr int Bn = 131072, Kn = 4096, Dn = 64;
constexpr int NCHUNK = 256;          // K / 16 codes per chunk (c fits in 8 bits)
constexpr int HCHUNK = 128;          // chunks per K-half
constexpr float TAU_S = 0.02f;       // covers split err ~1e-3 + 2x pack err ~4e-3

typedef short bf16x8 __attribute__((ext_vector_type(8)));
typedef float f32x4  __attribute__((ext_vector_type(4)));

__device__ __forceinline__ uint32_t rneb(float f) {           // bf16 RNE bits
    uint32_t u = __float_as_uint(f);
    return (u + 0x7FFFu + ((u >> 16) & 1u)) >> 16;
}
__device__ __forceinline__ float bfval(uint32_t b) { return __uint_as_float(b << 16); }

struct Split8 { bf16x8 hi, lo; };
__device__ __forceinline__ Split8 split8(float4 a, float4 b) {
    uint32_t h0=rneb(a.x),h1=rneb(a.y),h2=rneb(a.z),h3=rneb(a.w);
    uint32_t h4=rneb(b.x),h5=rneb(b.y),h6=rneb(b.z),h7=rneb(b.w);
    uint32_t l0=rneb(a.x-bfval(h0)), l1=rneb(a.y-bfval(h1));
    uint32_t l2=rneb(a.z-bfval(h2)), l3=rneb(a.w-bfval(h3));
    uint32_t l4=rneb(b.x-bfval(h4)), l5=rneb(b.y-bfval(h5));
    uint32_t l6=rneb(b.z-bfval(h6)), l7=rneb(b.w-bfval(h7));
    union { bf16x8 v; uint32_t u[4]; } H, L;
    H.u[0]=h0|(h1<<16); H.u[1]=h2|(h3<<16); H.u[2]=h4|(h5<<16); H.u[3]=h6|(h7<<16);
    L.u[0]=l0|(l1<<16); L.u[1]=l2|(l3<<16); L.u[2]=l4|(l5<<16); L.u[3]=l6|(l7<<16);
    Split8 r; r.hi = H.v; r.lo = L.v; return r;
}

// ---- prep: codebook -> fragment-major split-bf16 image (4KB per 16-code chunk) ----
__global__ __launch_bounds__(256) void vq_prep(const float* __restrict__ cb,
                                               uint8_t* __restrict__ stage,
                                               float* __restrict__ negcn) {
    int t = blockIdx.x * 256 + threadIdx.x;     // 0..32767, one per 8 floats
    int code = t >> 3, oct = t & 7;
    const float4* cp = (const float4*)(cb + (size_t)code * Dn + oct * 8);
    float4 f0 = cp[0], f1 = cp[1];
    Split8 s = split8(f0, f1);
    int j = code & 15, cc = code >> 4;
    uint8_t* base = stage + (size_t)cc * 4096;
    int dsto = (((oct & 3) * 16 + j) << 4) + ((oct & 4) ? 1024 : 0);
    *(bf16x8*)(base + dsto)        = s.hi;
    *(bf16x8*)(base + 2048 + dsto) = s.lo;
    float n = f0.x*f0.x + f0.y*f0.y + f0.z*f0.z + f0.w*f0.w
            + f1.x*f1.x + f1.y*f1.y + f1.z*f1.z + f1.w*f1.w;
    n += __shfl_xor(n, 1); n += __shfl_xor(n, 2); n += __shfl_xor(n, 4);
    if (oct == 0) negcn[code] = -0.5f * n;
}

__global__ void vq_zero(float* __restrict__ loss_acc, int* __restrict__ flag_cnt) {
    *loss_acc = 0.0f; *flag_cnt = 0;
}

// 1024 blocks x 256 thr; 4 waves: (row-tile = w>>1) x (K-half = w&1); 64 rows/wave.
__global__ __launch_bounds__(256, 3) void vq_main(
    const float* __restrict__ x, const uint8_t* __restrict__ stage,
    const float* __restrict__ negcn, const float* __restrict__ cb,
    float* __restrict__ out, float* __restrict__ loss_acc,
    int* __restrict__ flag_cnt, int* __restrict__ flag_rows) {

    __shared__ float sneg[Kn];                       // -0.5|c|^2
    __shared__ float smv1[4][64], smv2[4][64];
    __shared__ int   smk[4][64];
    __shared__ int   sres[128];

    const int tid = threadIdx.x;
    const int lane = tid & 63, w = tid >> 6;
    const int g = lane >> 4, j = lane & 15;
    const int kh = w & 1;                // K-half
    const int cstart = kh * HCHUNK;

    #pragma unroll
    for (int i = 0; i < 16; ++i) sneg[i*256 + tid] = negcn[i*256 + tid];

    // A fragments: 4 sub-tiles of 16 rows (A layout: row=lane&15, k=(lane>>4)*8+e)
    const int rowbase = blockIdx.x * 128 + (w >> 1) * 64;
    bf16x8 ah[4][2], al[4][2];
    #pragma unroll
    for (int t = 0; t < 4; ++t) {
        const float* xr = x + (size_t)(rowbase + t*16 + j) * Dn + g*8;
        Split8 s0 = split8(*(const float4*)xr,        *(const float4*)(xr + 4));
        Split8 s1 = split8(*(const float4*)(xr + 32), *(const float4*)(xr + 36));
        ah[t][0] = s0.hi; al[t][0] = s0.lo;
        ah[t][1] = s1.hi; al[t][1] = s1.lo;
    }

    // packed top-2: score low byte carries the chunk index (b1 >= b2 invariant)
    float b1[16], b2[16];
    #pragma unroll
    for (int s = 0; s < 16; ++s) { b1[s] = -3.4e38f; b2[s] = -3.4e38f; }

    // 2-deep register prefetch of B fragments straight from L2 (no LDS, no barriers)
    const uint8_t* sp = stage + (lane << 4);
    bf16x8 Bf[2][4];
    #pragma unroll
    for (int p = 0; p < 2; ++p) {
        const uint8_t* bbp = sp + ((size_t)(cstart + p) << 12);
        Bf[p][0] = *(const bf16x8*)(bbp);
        Bf[p][1] = *(const bf16x8*)(bbp + 1024);
        Bf[p][2] = *(const bf16x8*)(bbp + 2048);
        Bf[p][3] = *(const bf16x8*)(bbp + 3072);
    }
    __syncthreads();     // sneg visible

#define TOP2(ACC, BASE)                                                       \
    _Pragma("unroll")                                                         \
    for (int q = 0; q < 4; ++q) {                                             \
        int s = (BASE) + q;                                                   \
        uint32_t vb = (__float_as_uint(ACC[q]) & 0xFFFFFF00u) | (uint32_t)c_; \
        float vp = __uint_as_float(vb);                                       \
        float ob1 = b1[s];                                                    \
        b2[s] = __builtin_amdgcn_fmed3f(vp, ob1, b2[s]);                      \
        b1[s] = fmaxf(ob1, vp);                                               \
    }

#define CHUNK_BODY(P, C, RELOAD)                                              \
    {                                                                         \
        const uint32_t c_ = (uint32_t)(C);                                    \
        bf16x8 B0 = Bf[P][0], B1 = Bf[P][1], B2 = Bf[P][2], B3 = Bf[P][3];    \
        float nc = sneg[((int)c_ << 4) + j];                                  \
        f32x4 a0 = {nc,nc,nc,nc}, a1 = {nc,nc,nc,nc};                         \
        f32x4 a2 = {nc,nc,nc,nc}, a3 = {nc,nc,nc,nc};                         \
        a0 = __builtin_amdgcn_mfma_f32_16x16x32_bf16(ah[0][0], B0, a0, 0,0,0);\
        a1 = __builtin_amdgcn_mfma_f32_16x16x32_bf16(ah[1][0], B0, a1, 0,0,0);\
        a2 = __builtin_amdgcn_mfma_f32_16x16x32_bf16(ah[2][0], B0, a2, 0,0,0);\
        a3 = __builtin_amdgcn_mfma_f32_16x16x32_bf16(ah[3][0], B0, a3, 0,0,0);\
        a0 = __builtin_amdgcn_mfma_f32_16x16x32_bf16(ah[0][1], B1, a0, 0,0,0);\
        a1 = __builtin_amdgcn_mfma_f32_16x16x32_bf16(ah[1][1], B1, a1, 0,0,0);\
        a2 = __builtin_amdgcn_mfma_f32_16x16x32_bf16(ah[2][1], B1, a2, 0,0,0);\
        a3 = __builtin_amdgcn_mfma_f32_16x16x32_bf16(ah[3][1], B1, a3, 0,0,0);\
        a0 = __builtin_amdgcn_mfma_f32_16x16x32_bf16(al[0][0], B0, a0, 0,0,0);\
        a1 = __builtin_amdgcn_mfma_f32_16x16x32_bf16(al[1][0], B0, a1, 0,0,0);\
        a2 = __builtin_amdgcn_mfma_f32_16x16x32_bf16(al[2][0], B0, a2, 0,0,0);\
        a3 = __builtin_amdgcn_mfma_f32_16x16x32_bf16(al[3][0], B0, a3, 0,0,0);\
        a0 = __builtin_amdgcn_mfma_f32_16x16x32_bf16(al[0][1], B1, a0, 0,0,0);\
        a1 = __builtin_amdgcn_mfma_f32_16x16x32_bf16(al[1][1], B1, a1, 0,0,0);\
        a2 = __builtin_amdgcn_mfma_f32_16x16x32_bf16(al[2][1], B1, a2, 0,0,0);\
        a3 = __builtin_amdgcn_mfma_f32_16x16x32_bf16(al[3][1], B1, a3, 0,0,0);\
        a0 = __builtin_amdgcn_mfma_f32_16x16x32_bf16(ah[0][0], B2, a0, 0,0,0);\
        a1 = __builtin_amdgcn_mfma_f32_16x16x32_bf16(ah[1][0], B2, a1, 0,0,0);\
        a2 = __builtin_amdgcn_mfma_f32_16x16x32_bf16(ah[2][0], B2, a2, 0,0,0);\
        a3 = __builtin_amdgcn_mfma_f32_16x16x32_bf16(ah[3][0], B2, a3, 0,0,0);\
        a0 = __builtin_amdgcn_mfma_f32_16x16x32_bf16(ah[0][1], B3, a0, 0,0,0);\
        a1 = __builtin_amdgcn_mfma_f32_16x16x32_bf16(ah[1][1], B3, a1, 0,0,0);\
        a2 = __builtin_amdgcn_mfma_f32_16x16x32_bf16(ah[2][1], B3, a2, 0,0,0);\
        a3 = __builtin_amdgcn_mfma_f32_16x16x32_bf16(ah[3][1], B3, a3, 0,0,0);\
        if (RELOAD) {   /* prefetch chunk c_+2 into this slot */              \
            const uint8_t* nb = sp + ((size_t)(c_ + 2) << 12);                \
            Bf[P][0] = *(const bf16x8*)(nb);                                  \
            Bf[P][1] = *(const bf16x8*)(nb + 1024);                           \
            Bf[P][2] = *(const bf16x8*)(nb + 2048);                           \
            Bf[P][3] = *(const bf16x8*)(nb + 3072);                           \
        }                                                                     \
        TOP2(a0, 0) TOP2(a1, 4) TOP2(a2, 8) TOP2(a3, 12)                      \
    }

    #pragma unroll 1
    for (int c4 = cstart; c4 < cstart + HCHUNK - 2; c4 += 2) {
        CHUNK_BODY(0, c4 + 0, true)
        CHUNK_BODY(1, c4 + 1, true)
    }
    CHUNK_BODY(0, cstart + HCHUNK - 2, false)
    CHUNK_BODY(1, cstart + HCHUNK - 1, false)
#undef CHUNK_BODY
#undef TOP2

    // per-row merge across the 16 code-lanes (D layout: row=(lane>>4)*4+q, col=lane&15)
    #pragma unroll
    for (int s = 0; s < 16; ++s) {
        float v1 = b1[s], v2 = b2[s];
        int kk = (int)((__float_as_uint(v1) & 0xFFu) << 4) + j;   // c*16 + j
        #pragma unroll
        for (int m = 1; m < 16; m <<= 1) {
            float p1 = __shfl_xor(v1, m);
            float p2 = __shfl_xor(v2, m);
            int pk = __shfl_xor(kk, m);
            v2 = fmaxf(fmaxf(v2, p2), fminf(v1, p1));
            bool take = (p1 > v1) || ((p1 == v1) && (pk < kk));
            v1 = take ? p1 : v1;
            kk = take ? pk : kk;
        }
        if (j == 0) {
            int row = (s >> 2)*16 + g*4 + (s & 3);   // 0..63 within wave
            smv1[w][row] = v1; smv2[w][row] = v2; smk[w][row] = kk;
        }
    }
    __syncthreads();

    // cross-K-half merge (disjoint k-ranges; near-ties all fall under TAU -> cleanup)
    if (tid < 128) {
        int rt = tid >> 6, r = tid & 63;
        int wa = rt * 2, wb = wa + 1;
        float v1a = smv1[wa][r], v2a = smv2[wa][r];
        float v1b = smv1[wb][r], v2b = smv2[wb][r];
        int   ka  = smk[wa][r],  kb  = smk[wb][r];
        bool take = v1b > v1a;
        float m1 = take ? v1b : v1a;
        int   kk = take ? kb  : ka;
        float m2 = fmaxf(fmaxf(v2a, v2b), fminf(v1a, v1b));
        int flag = ((m1 - m2) < TAU_S) ? (int)0x80000000 : 0;
        sres[tid] = kk | flag;
    }
    __syncthreads();

    // epilogue: fully coalesced; f enumerates (row, float4) pairs; 128 rows/block
    float ls = 0.f;
    const size_t blockrow = (size_t)blockIdx.x * 128;
    #pragma unroll 1
    for (int it = 0; it < 8; ++it) {
        int f = it * 256 + tid;
        int r = f >> 4, q = f & 15;
        int pk = sres[r];
        int idx = pk & 0x7FFFFFFF;
        bool flagged = pk < 0;
        size_t grow = blockrow + r;
        float4 xx = ((const float4*)(x + grow * Dn))[q];
        float4 qq = ((const float4*)(cb + (size_t)idx * Dn))[q];
        float dx = qq.x - xx.x, dy = qq.y - xx.y, dz = qq.z - xx.z, dw = qq.w - xx.w;
        float4 o; o.x = xx.x + dx; o.y = xx.y + dy; o.z = xx.z + dz; o.w = xx.w + dw;
        ((float4*)(out + grow * Dn))[q] = o;
        if (flagged) {
            if (q == 0) { int p = atomicAdd(flag_cnt, 1); flag_rows[p] = (int)grow; }
        } else {
            ls = fmaf(dx, dx, ls); ls = fmaf(dy, dy, ls);
            ls = fmaf(dz, dz, ls); ls = fmaf(dw, dw, ls);
        }
    }
    #pragma unroll
    for (int m = 1; m < 64; m <<= 1) ls += __shfl_xor(ls, m);
    if (lane == 0) atomicAdd(loss_acc, ls);
}

// fp64 full rescan of flagged rows, 4 rows per block-iteration (codebook read shared).
__global__ __launch_bounds__(256) void vq_cleanup(
    const float* __restrict__ x, const float* __restrict__ cb,
    const int* __restrict__ flag_cnt, const int* __restrict__ flag_rows,
    float* __restrict__ out, float* __restrict__ loss_acc) {
    __shared__ double sxd[4][Dn];
    __shared__ double swb[4][4];
    __shared__ int    swi[4][4];
    const int tid = threadIdx.x;
    const int n = *flag_cnt;

    for (int it = blockIdx.x; it * 4 < n; it += gridDim.x) {
        const int base = it * 4;
        const int nr = min(4, n - base);
        __syncthreads();   // protect sxd/swb from previous iteration readers
        {
            int rr = tid >> 6, e = tid & 63;
            int row = flag_rows[base + ((rr < nr) ? rr : 0)];
            sxd[rr][e] = (double)x[(size_t)row * Dn + e];
        }
        __syncthreads();

        double best[4]; int bidx[4];
        #pragma unroll
        for (int r2 = 0; r2 < 4; ++r2) { best[r2] = 1.0e300; bidx[r2] = 0x7FFFFFFF; }

        #pragma unroll 1
        for (int i = 0; i < Kn / 256; ++i) {          // 16 codes per thread
            const int k = i * 256 + tid;
            const float* c4 = cb + (size_t)k * Dn;
            double cn = 0.0;
            double d0 = 0.0, d1 = 0.0, d2 = 0.0, d3 = 0.0;
            #pragma unroll 8
            for (int e = 0; e < Dn; ++e) {
                double ce = (double)c4[e];
                cn = fma(ce, ce, cn);
                d0 = fma(ce, sxd[0][e], d0);
                d1 = fma(ce, sxd[1][e], d1);
                d2 = fma(ce, sxd[2][e], d2);
                d3 = fma(ce, sxd[3][e], d3);
            }
            double dd[4] = { cn - 2.0*d0, cn - 2.0*d1, cn - 2.0*d2, cn - 2.0*d3 };
            #pragma unroll
            for (int r2 = 0; r2 < 4; ++r2)
                if (dd[r2] < best[r2] || (dd[r2] == best[r2] && k < bidx[r2])) {
                    best[r2] = dd[r2]; bidx[r2] = k;
                }
        }
        // wave argmin then cross-wave merge (first-occurrence ties)
        #pragma unroll
        for (int r2 = 0; r2 < 4; ++r2) {
            double bb = best[r2]; int bi = bidx[r2];
            #pragma unroll
            for (int m = 1; m < 64; m <<= 1) {
                double pb = __shfl_xor(bb, m);
                int    pi = __shfl_xor(bi, m);
                if (pb < bb || (pb == bb && pi < bi)) { bb = pb; bi = pi; }
            }
            if ((tid & 63) == 0) { swb[r2][tid >> 6] = bb; swi[r2][tid >> 6] = bi; }
        }
        __syncthreads();
        if (tid < 4) {
            double fb = swb[tid][0]; int fi = swi[tid][0];
            #pragma unroll
            for (int wv = 1; wv < 4; ++wv) {
                double pb = swb[tid][wv]; int pi = swi[tid][wv];
                if (pb < fb || (pb == fb && pi < fi)) { fb = pb; fi = pi; }
            }
            swi[tid][0] = fi;
        }
        __syncthreads();

        if (tid < 64) {
            int r2 = tid >> 4, q = tid & 15;
            if (r2 < nr) {
                int row = flag_rows[base + r2];
                int fi  = swi[r2][0];
                float4 xx = ((const float4*)(x + (size_t)row * Dn))[q];
                float4 qq = ((const float4*)(cb + (size_t)fi * Dn))[q];
                float dx = qq.x - xx.x, dy = qq.y - xx.y, dz = qq.z - xx.z, dw = qq.w - xx.w;
                float4 o; o.x = xx.x + dx; o.y = xx.y + dy; o.z = xx.z + dz; o.w = xx.w + dw;
                ((float4*)(out + (size_t)row * Dn))[q] = o;
                float ls = dx*dx + dy*dy + dz*dz + dw*dw;
                ls += __shfl_xor(ls, 1); ls += __shfl_xor(ls, 2);
                ls += __shfl_xor(ls, 4); ls += __shfl_xor(ls, 8);
                if (q == 0) atomicAdd(loss_acc, ls);
            }
        }
    }
}

__global__ void vq_final(float* __restrict__ loss_acc) {
    *loss_acc = *loss_acc * (1.25f / (float)(Bn * Dn));
}

extern "C" void kernel_launch(void* const* d_in, const int* in_sizes, int n_in,
                              void* d_out, int out_size, void* d_ws, size_t ws_size,
                              hipStream_t stream) {
    const float* x  = (const float*)d_in[0];
    const float* cb = (const float*)d_in[1];
    float* out  = (float*)d_out;
    float* loss = out + (size_t)Bn * Dn;

    // ws layout: [negcn 16KB][stage 1MB][flag_cnt 4B][flag_rows 512KB]
    uint8_t* wsb = (uint8_t*)d_ws;
    float*   negcn     = (float*)wsb;
    uint8_t* stage     = wsb + 16384;
    int*     flag_cnt  = (int*)(wsb + 16384 + (size_t)NCHUNK * 4096);
    int*     flag_rows = flag_cnt + 1;

    vq_prep<<<128, 256, 0, stream>>>(cb, stage, negcn);
    vq_zero<<<1, 1, 0, stream>>>(loss, flag_cnt);
    vq_main<<<Bn / 128, 256, 0, stream>>>(x, stage, negcn, cb, out, loss, flag_cnt, flag_rows);
    vq_cleanup<<<512, 256, 0, stream>>>(x, cb, flag_cnt, flag_rows, out, loss);
    vq_final<<<1, 1, 0, stream>>>(loss);
}